// Round 1
// baseline (64.354 us; speedup 1.0000x reference)
//
#include <hip/hip_runtime.h>
#include <math.h>

#define NH 128   // hidden
#define NP 7     // particles
#define ND 16    // per-particle dim
#define NF 112   // NP*ND
#define NB 128   // batch

#define CC 2.8853900817779268f   // 2*log2(e)

// r(x) = 1/(exp(2x)+1), so tanh(x) = 1 - 2*r(x)
__device__ __forceinline__ float rterm(float x) {
  return __builtin_amdgcn_rcpf(__builtin_amdgcn_exp2f(x * CC) + 1.0f);
}

// pair (a,b), a<b at positions 5,6:
//   sA = s4 + G5[a] + G6[b]  (even),  sB = s4 + G5[b] + G6[a]  (odd)
//   sign*(tanh(sA) - tanh(sB)) = 2*sign*(r(sB) - r(sA));  factor 2 applied at the end
__device__ __forceinline__ void pair_acc(float s40, float s41,
                                         float2 g5a, float2 g6a,
                                         float2 g5b, float2 g6b,
                                         float sgn, float& a0, float& a1) {
  float sA0 = s40 + g5a.x + g6b.x;
  float sB0 = s40 + g5b.x + g6a.x;
  float sA1 = s41 + g5a.y + g6b.y;
  float sB1 = s41 + g5b.y + g6a.y;
  float d0 = rterm(sB0) - rterm(sA0);
  float d1 = rterm(sB1) - rterm(sA1);
  a0 = fmaf(sgn, d0, a0);
  a1 = fmaf(sgn, d1, a1);
}

#define GLD(i, j) (*(const float2*)&gsh[((i) * 7 + (j)) * NH + (lane << 1)])

// t3 = EK (parity digit gives sgk), remaining trio P<Q<R at positions 4,5,6
#define T3STEP(sgk, EK, P, Q, R) do {                                   \
    float2 g3 = GLD(3, EK);                                             \
    float s30 = s20 + g3.x, s31 = s21 + g3.y;                           \
    float2 g4p = GLD(4, P), g4q = GLD(4, Q), g4r = GLD(4, R);           \
    float2 g5p = GLD(5, P), g5q = GLD(5, Q), g5r = GLD(5, R);           \
    float2 g6p = GLD(6, P), g6q = GLD(6, Q), g6r = GLD(6, R);           \
    pair_acc(s30 + g4p.x, s31 + g4p.y, g5q, g6q, g5r, g6r,  (sgk), acc0, acc1); \
    pair_acc(s30 + g4q.x, s31 + g4q.y, g5p, g6p, g5r, g6r, -(sgk), acc0, acc1); \
    pair_acc(s30 + g4r.x, s31 + g4r.y, g5p, g6p, g5q, g6q,  (sgk), acc0, acc1); \
  } while (0)

extern "C" __global__ void __launch_bounds__(512, 1)
antisym_leaf_kernel(const float* __restrict__ x0, const float* __restrict__ x1,
                    const float* __restrict__ W0, const float* __restrict__ b0,
                    const float* __restrict__ V0,
                    const float* __restrict__ W1, const float* __restrict__ b1,
                    const float* __restrict__ V1,
                    float* __restrict__ ws) {
  __shared__ float gsh[49 * NH];   // G[i][j][h]
  __shared__ float xs[NF];
  __shared__ float red[8];

  const int tid  = threadIdx.x;
  const int leaf = blockIdx.x >> 7;
  const int b    = blockIdx.x & 127;

  const float* xL = leaf ? x1 : x0;
  const float* WL = leaf ? W1 : W0;
  const float* bL = leaf ? b1 : b0;
  const float* vL = leaf ? V1 : V0;

  // ---- Phase A: stage x row, build G[i][j][h] in LDS ----
  if (tid < NF) xs[tid] = xL[b * NF + tid];
  __syncthreads();

  for (int idx = tid; idx < 49 * NH; idx += 512) {
    int h  = idx & (NH - 1);
    int ij = idx >> 7;          // 0..48
    int i  = ij / 7;
    int j  = ij - 7 * i;
    const float* wp = WL + i * ND * NH + h;   // coalesced over h
    const float* xp = xs + j * ND;
    float v = 0.f;
#pragma unroll
    for (int k = 0; k < ND; ++k) v = fmaf(xp[k], wp[k * NH], v);
    gsh[idx] = v;
  }
  __syncthreads();

  // ---- Phase B: tree-enumerate all 5040 permutations ----
  const int lane = tid & 63;
  const int wid  = tid >> 6;    // 0..7
  float2 bias2 = ((const float2*)bL)[lane];
  float2 V2    = ((const float2*)vL)[lane];
  float acc0 = 0.f, acc1 = 0.f;

  int m = 0;  // linear index over the 210 (t0,t1,t2) triples
#pragma unroll 1
  for (int t0 = 0; t0 < 7; ++t0) {
    float sg0 = (t0 & 1) ? -1.f : 1.f;
    float2 g0 = GLD(0, t0);
    float s00 = bias2.x + g0.x, s01 = bias2.y + g0.y;
    int c1 = 0;
#pragma unroll 1
    for (int t1 = 0; t1 < 7; ++t1) {
      if (t1 == t0) continue;
      float sg1 = (c1 & 1) ? -sg0 : sg0; ++c1;
      float2 g1 = GLD(1, t1);
      float s10 = s00 + g1.x, s11 = s01 + g1.y;
      int c2 = 0;
#pragma unroll 1
      for (int t2 = 0; t2 < 7; ++t2) {
        if (t2 == t0 || t2 == t1) continue;
        float sg2 = (c2 & 1) ? -sg1 : sg1; ++c2;
        if ((m++ & 7) != wid) continue;   // round-robin triples over waves
        float2 g2 = GLD(2, t2);
        float s20 = s10 + g2.x, s21 = s11 + g2.y;
        int rm = 0x7F & ~((1 << t0) | (1 << t1) | (1 << t2));
        int e0 = __ffs(rm) - 1; rm &= rm - 1;
        int e1 = __ffs(rm) - 1; rm &= rm - 1;
        int e2 = __ffs(rm) - 1; rm &= rm - 1;
        int e3 = __ffs(rm) - 1;
        T3STEP( sg2, e0, e1, e2, e3);
        T3STEP(-sg2, e1, e0, e2, e3);
        T3STEP( sg2, e2, e0, e1, e3);
        T3STEP(-sg2, e3, e0, e1, e2);
      }
    }
  }

  // ---- Reduce: psi = 2 * sum_h V[h] * acc[h] ----
  float part = V2.x * acc0 + V2.y * acc1;
#pragma unroll
  for (int off = 32; off > 0; off >>= 1) part += __shfl_xor(part, off, 64);
  if (lane == 0) red[wid] = part;
  __syncthreads();
  if (tid == 0) {
    float tot = 0.f;
#pragma unroll
    for (int w = 0; w < 8; ++w) tot += red[w];
    ws[leaf * NB + b] = 2.0f * tot;
  }
}

extern "C" __global__ void finalize_kernel(const float* __restrict__ ws,
                                           float* __restrict__ out) {
  int t = threadIdx.x;
  if (t < NB) {
    float p0 = ws[t];
    float p1 = ws[NB + t];
    float s0 = (p0 > 0.f) ? 1.f : ((p0 < 0.f) ? -1.f : 0.f);
    float s1 = (p1 > 0.f) ? 1.f : ((p1 < 0.f) ? -1.f : 0.f);
    out[t]      = s0 * s1;                       // sign
    out[NB + t] = logf(fabsf(p0)) + logf(fabsf(p1));  // logabs
  }
}

extern "C" void kernel_launch(void* const* d_in, const int* in_sizes, int n_in,
                              void* d_out, int out_size, void* d_ws, size_t ws_size,
                              hipStream_t stream) {
  const float* x0 = (const float*)d_in[0];
  const float* x1 = (const float*)d_in[1];
  const float* W0 = (const float*)d_in[2];
  const float* b0 = (const float*)d_in[3];
  const float* V0 = (const float*)d_in[4];
  // d_in[5] = c0: cancels under antisymmetrization (sum of signs == 0)
  const float* W1 = (const float*)d_in[6];
  const float* b1 = (const float*)d_in[7];
  const float* V1 = (const float*)d_in[8];
  // d_in[9] = c1: cancels

  float* ws  = (float*)d_ws;      // 256 floats: psi0[128], psi1[128]
  float* out = (float*)d_out;     // 256 floats: sign[128], logabs[128]

  antisym_leaf_kernel<<<2 * NB, 512, 0, stream>>>(x0, x1, W0, b0, V0, W1, b1, V1, ws);
  finalize_kernel<<<1, NB, 0, stream>>>(ws, out);
}

// Round 2
// 59.004 us; speedup vs baseline: 1.0907x; 1.0907x over previous
//
#include <hip/hip_runtime.h>
#include <math.h>

#define NH 128   // hidden
#define NP 7     // particles
#define ND 16    // per-particle dim
#define NF 112   // NP*ND
#define NB 128   // batch

#define CC 2.8853900817779268f   // 2*log2(e): exp2(CC*s) = e^{2s}

typedef float f2 __attribute__((ext_vector_type(2)));

__device__ __forceinline__ float rcpf(float x) { return __builtin_amdgcn_rcpf(x); }

// Pair (a,b) at positions 5,6 under prefix-exp E4 (= e^{2*(b + g0..g4)}):
//   eA = E4*p5a*p6b (even perm), eB = E4*p5b*p6a (odd perm)
//   sgn*(tanh(sA)-tanh(sB)) = 2*sgn*(eA-eB)/((1+eA)(1+eB)); factor 2 at the end
__device__ __forceinline__ void pair_acc(f2 E4, f2 p5a, f2 p6a, f2 p5b, f2 p6b,
                                         float sgn, f2& acc) {
  f2 t = p5a * p6b;
  f2 u = p5b * p6a;
  f2 ea = E4 * t;
  f2 eb = E4 * u;
  f2 num = ea - eb;
  f2 e1 = ea + 1.0f;
  f2 e2 = eb + 1.0f;
  f2 den = e1 * e2;
  f2 rd;
  rd.x = rcpf(den.x);
  rd.y = rcpf(den.y);
  acc += sgn * (num * rd);
}

#define GLD(i, j) (*(const f2*)&psh[((i) * 7 + (j)) * NH + (lane << 1)])

// position-3 element EK (sign SGK), remaining trio P<Q<R at positions 4,5,6
#define T3STEP(SGK, EK, P, Q, R) do {                                   \
    f2 E3 = E2 * GLD(3, EK);                                            \
    f2 p4p = GLD(4, P), p4q = GLD(4, Q), p4r = GLD(4, R);               \
    f2 p5p = GLD(5, P), p5q = GLD(5, Q), p5r = GLD(5, R);               \
    f2 p6p = GLD(6, P), p6q = GLD(6, Q), p6r = GLD(6, R);               \
    pair_acc(E3 * p4p, p5q, p6q, p5r, p6r,  (SGK), acc);                \
    pair_acc(E3 * p4q, p5p, p6p, p5r, p6r, -(SGK), acc);                \
    pair_acc(E3 * p4r, p5p, p6p, p5q, p6q,  (SGK), acc);                \
  } while (0)

extern "C" __global__ void __launch_bounds__(512, 4)
antisym_leaf_kernel(const float* __restrict__ x0, const float* __restrict__ x1,
                    const float* __restrict__ W0, const float* __restrict__ b0,
                    const float* __restrict__ V0,
                    const float* __restrict__ W1, const float* __restrict__ b1,
                    const float* __restrict__ V1,
                    float* __restrict__ ws) {
  __shared__ float psh[49 * NH];   // P[i][j][h] = exp(2*G[i][j][h])
  __shared__ float xs[NF];
  __shared__ float red[8];

  const int tid  = threadIdx.x;
  const int bid  = blockIdx.x;          // [0, 512)
  const int leaf = bid >> 8;
  const int b    = bid & 127;
  const int half = (bid >> 7) & 1;

  const float* xL = leaf ? x1 : x0;
  const float* WL = leaf ? W1 : W0;
  const float* bL = leaf ? b1 : b0;
  const float* vL = leaf ? V1 : V0;

  // ---- Phase A: stage x row, build P[i][j][h] = exp(2*x_j . W_i[:,h]) in LDS ----
  if (tid < NF) xs[tid] = xL[b * NF + tid];
  __syncthreads();

  for (int idx = tid; idx < 49 * NH; idx += 512) {
    int h  = idx & (NH - 1);
    int ij = idx >> 7;          // 0..48
    int i  = ij / 7;
    int j  = ij - 7 * i;
    const float* wp = WL + i * ND * NH + h;   // coalesced over h
    const float* xp = xs + j * ND;
    float v = 0.f;
#pragma unroll
    for (int k = 0; k < ND; ++k) v = fmaf(xp[k], wp[k * NH], v);
    psh[idx] = __builtin_amdgcn_exp2f(v * CC);
  }
  __syncthreads();

  // ---- Phase B: tree-enumerate all 5040 permutations via prefix-exp products ----
  const int lane = tid & 63;
  const int wid  = tid >> 6;            // 0..7
  const int slot = (half << 3) | wid;   // 0..15

  f2 bias2 = ((const f2*)bL)[lane];
  f2 V2    = ((const f2*)vL)[lane];
  f2 Eb;
  Eb.x = __builtin_amdgcn_exp2f(bias2.x * CC);
  Eb.y = __builtin_amdgcn_exp2f(bias2.y * CC);
  f2 acc = {0.f, 0.f};

  int m = 0;  // linear index over the 210 (t0,t1,t2) triples
#pragma unroll 1
  for (int t0 = 0; t0 < 7; ++t0) {
    float sg0 = (t0 & 1) ? -1.f : 1.f;
    f2 E0 = Eb * GLD(0, t0);
    int c1 = 0;
#pragma unroll 1
    for (int t1 = 0; t1 < 7; ++t1) {
      if (t1 == t0) continue;
      float sg1 = (c1 & 1) ? -sg0 : sg0; ++c1;
      f2 E1 = E0 * GLD(1, t1);
      int c2 = 0;
#pragma unroll 1
      for (int t2 = 0; t2 < 7; ++t2) {
        if (t2 == t0 || t2 == t1) continue;
        float sg2 = (c2 & 1) ? -sg1 : sg1; ++c2;
        if ((m++ & 15) != slot) continue;   // round-robin triples over 16 wave-slots
        f2 E2 = E1 * GLD(2, t2);
        int rm = 0x7F & ~((1 << t0) | (1 << t1) | (1 << t2));
        int e0 = __ffs(rm) - 1; rm &= rm - 1;
        int e1 = __ffs(rm) - 1; rm &= rm - 1;
        int e2i = __ffs(rm) - 1; rm &= rm - 1;
        int e3 = __ffs(rm) - 1;
        T3STEP( sg2, e0, e1, e2i, e3);
        T3STEP(-sg2, e1, e0, e2i, e3);
        T3STEP( sg2, e2i, e0, e1, e3);
        T3STEP(-sg2, e3, e0, e1, e2i);
      }
    }
  }

  // ---- Reduce: partial psi = sum_h V[h] * acc[h] (factor 2 in finalize) ----
  float part = V2.x * acc.x + V2.y * acc.y;
#pragma unroll
  for (int off = 32; off > 0; off >>= 1) part += __shfl_xor(part, off, 64);
  if (lane == 0) red[wid] = part;
  __syncthreads();
  if (tid == 0) {
    float tot = 0.f;
#pragma unroll
    for (int w = 0; w < 8; ++w) tot += red[w];
    ws[leaf * 256 + half * 128 + b] = tot;
  }
}

extern "C" __global__ void finalize_kernel(const float* __restrict__ ws,
                                           float* __restrict__ out) {
  int t = threadIdx.x;
  if (t < NB) {
    float p0 = 2.0f * (ws[t] + ws[128 + t]);
    float p1 = 2.0f * (ws[256 + t] + ws[384 + t]);
    float s0 = (p0 > 0.f) ? 1.f : ((p0 < 0.f) ? -1.f : 0.f);
    float s1 = (p1 > 0.f) ? 1.f : ((p1 < 0.f) ? -1.f : 0.f);
    out[t]      = s0 * s1;                            // sign
    out[NB + t] = logf(fabsf(p0)) + logf(fabsf(p1));  // logabs
  }
}

extern "C" void kernel_launch(void* const* d_in, const int* in_sizes, int n_in,
                              void* d_out, int out_size, void* d_ws, size_t ws_size,
                              hipStream_t stream) {
  const float* x0 = (const float*)d_in[0];
  const float* x1 = (const float*)d_in[1];
  const float* W0 = (const float*)d_in[2];
  const float* b0 = (const float*)d_in[3];
  const float* V0 = (const float*)d_in[4];
  // d_in[5] = c0: cancels under antisymmetrization (sum of signs == 0)
  const float* W1 = (const float*)d_in[6];
  const float* b1 = (const float*)d_in[7];
  const float* V1 = (const float*)d_in[8];
  // d_in[9] = c1: cancels

  float* ws  = (float*)d_ws;      // 512 floats: psi partials [leaf][half][b]
  float* out = (float*)d_out;     // 256 floats: sign[128], logabs[128]

  antisym_leaf_kernel<<<512, 512, 0, stream>>>(x0, x1, W0, b0, V0, W1, b1, V1, ws);
  finalize_kernel<<<1, NB, 0, stream>>>(ws, out);
}